// Round 2
// baseline (1418.440 us; speedup 1.0000x reference)
//
#include <hip/hip_runtime.h>
#include <cstdint>

#define B_ 4096
#define D_ 1024
#define H_ 2048
#define E_ 8

#define BM 128
#define BN 128
#define BK 64

typedef __attribute__((ext_vector_type(8))) short short8;
typedef __attribute__((ext_vector_type(4))) float f32x4;
typedef unsigned short u16;
typedef unsigned int u32;

// ---------- bf16 helpers (RNE) ----------
__device__ __forceinline__ u16 f2bf(float f) {
  u32 u = __builtin_bit_cast(u32, f);
  u32 r = (u + 0x7fffu + ((u >> 16) & 1u)) >> 16;
  return (u16)r;
}
__device__ __forceinline__ float bf2f(u16 h) {
  return __builtin_bit_cast(float, (u32)h << 16);
}

// ---------- async global->LDS, 16B per lane ----------
// LDS dest is wave-uniform base + lane*16 (HW rule); low 32 bits of an LDS
// flat address are the LDS byte offset on gfx9 (aperture is 2^32-aligned).
__device__ __forceinline__ void gld_lds16(const void* g, void* l) {
  __builtin_amdgcn_global_load_lds(
      (const __attribute__((address_space(1))) u32*)(uintptr_t)g,
      (__attribute__((address_space(3))) u32*)(u32)(uintptr_t)l,
      16, 0, 0);
}

// ---------- split fp32 -> bf16 hi/lo ----------
__global__ __launch_bounds__(256)
void split_f32(const float* __restrict__ in, u16* __restrict__ hi,
               u16* __restrict__ lo, int n4) {
  int i = blockIdx.x * 256 + threadIdx.x;
  if (i >= n4) return;
  float4 v = ((const float4*)in)[i];
  float a[4] = {v.x, v.y, v.z, v.w};
  u16 hb[4], lb[4];
#pragma unroll
  for (int j = 0; j < 4; ++j) {
    hb[j] = f2bf(a[j]);
    lb[j] = f2bf(a[j] - bf2f(hb[j]));
  }
  ((ushort4*)hi)[i] = make_ushort4(hb[0], hb[1], hb[2], hb[3]);
  ((ushort4*)lo)[i] = make_ushort4(lb[0], lb[1], lb[2], lb[3]);
}

// ---------- split + transpose: in [E][R][C] fp32 -> out [E][C][R] bf16 hi/lo ----------
__global__ __launch_bounds__(256)
void split_transpose(const float* __restrict__ in, u16* __restrict__ thi,
                     u16* __restrict__ tlo, int R, int C) {
  __shared__ float t[32][33];
  const int e = blockIdx.z;
  const size_t base = (size_t)e * R * C;
  const int c0 = blockIdx.x * 32, r0 = blockIdx.y * 32;
  const int tx = threadIdx.x, ty = threadIdx.y;
#pragma unroll
  for (int i = 0; i < 32; i += 8)
    t[ty + i][tx] = in[base + (size_t)(r0 + ty + i) * C + (c0 + tx)];
  __syncthreads();
#pragma unroll
  for (int i = 0; i < 32; i += 8) {
    float v = t[tx][ty + i];
    u16 hb = f2bf(v);
    u16 lb = f2bf(v - bf2f(hb));
    size_t oidx = base + (size_t)(c0 + ty + i) * R + (r0 + tx);
    thi[oidx] = hb;
    tlo[oidx] = lb;
  }
}

// ---------- split-3 bf16 MFMA GEMM: C[M x N] = A[M x K] * Bt[N x K]^T ----------
// acc = Ah*Bh + Ah*Bl + Al*Bh (fp32 accum); lo*lo dropped (~2^-16 rel).
// RELU_SPLIT: C written as relu(acc+bias) split to bf16 hi/lo (ldC = N).
// else:       C written fp32 at Cf[row*ldC + col] = acc + bias[col].
template <bool RELU_SPLIT>
__global__ __launch_bounds__(256, 2)
void gemm_split3(const u16* __restrict__ Ah, const u16* __restrict__ Al,
                 const u16* __restrict__ Bth, const u16* __restrict__ Btl,
                 const float* __restrict__ bias,
                 u16* __restrict__ Chi, u16* __restrict__ Clo,
                 float* __restrict__ Cf, int K, int ldC) {
  __shared__ __align__(16) u16 sAh[BM][BK];
  __shared__ __align__(16) u16 sAl[BM][BK];
  __shared__ __align__(16) u16 sBh[BN][BK];
  __shared__ __align__(16) u16 sBl[BN][BK];

  const int tid = threadIdx.x;
  const int lane = tid & 63;
  const int w = tid >> 6;          // wave 0..3
  const int wm = w >> 1, wn = w & 1;
  const int m0 = blockIdx.y * BM;
  const int n0 = blockIdx.x * BN;

  const int rA = lane & 15;
  const int kg = lane >> 4;        // 0..3
  const int chunk = w << 2;        // 4 staging chunks per wave

  f32x4 acc[4][4];
#pragma unroll
  for (int m = 0; m < 4; ++m)
#pragma unroll
    for (int n = 0; n < 4; ++n)
      acc[m][n] = (f32x4){0.f, 0.f, 0.f, 0.f};

  for (int k0 = 0; k0 < K; k0 += BK) {
    __syncthreads();  // previous tile fully consumed
#pragma unroll
    for (int i = 0; i < 4; ++i) {
      const int o = ((chunk + i) << 10) + (lane << 4);  // byte off in 16KB tile
      const int r = o >> 7;                             // row (128B rows)
      const int ce = (o & 127) >> 1;                    // col element
      const size_t ga = (size_t)(m0 + r) * K + (k0 + ce);
      const size_t gb = (size_t)(n0 + r) * K + (k0 + ce);
      const int od = (chunk + i) << 9;                  // dest offset in u16
      gld_lds16(Ah + ga, &sAh[0][0] + od);
      gld_lds16(Al + ga, &sAl[0][0] + od);
      gld_lds16(Bth + gb, &sBh[0][0] + od);
      gld_lds16(Btl + gb, &sBl[0][0] + od);
    }
    __syncthreads();  // compiler drains vmcnt before s_barrier -> tile visible

#pragma unroll
    for (int kk = 0; kk < 2; ++kk) {
      const int ko = kk * 32 + kg * 8;
      short8 ah[4], al[4], bh[4], bl[4];
#pragma unroll
      for (int m = 0; m < 4; ++m) {
        ah[m] = *(const short8*)&sAh[wm * 64 + m * 16 + rA][ko];
        al[m] = *(const short8*)&sAl[wm * 64 + m * 16 + rA][ko];
      }
#pragma unroll
      for (int n = 0; n < 4; ++n) {
        bh[n] = *(const short8*)&sBh[wn * 64 + n * 16 + rA][ko];
        bl[n] = *(const short8*)&sBl[wn * 64 + n * 16 + rA][ko];
      }
#pragma unroll
      for (int m = 0; m < 4; ++m)
#pragma unroll
        for (int n = 0; n < 4; ++n) {
          acc[m][n] = __builtin_amdgcn_mfma_f32_16x16x32_bf16(ah[m], bh[n], acc[m][n], 0, 0, 0);
          acc[m][n] = __builtin_amdgcn_mfma_f32_16x16x32_bf16(ah[m], bl[n], acc[m][n], 0, 0, 0);
          acc[m][n] = __builtin_amdgcn_mfma_f32_16x16x32_bf16(al[m], bh[n], acc[m][n], 0, 0, 0);
        }
    }
  }

  // epilogue: C/D layout col=lane&15, row=(lane>>4)*4+reg  [m89-verified]
#pragma unroll
  for (int m = 0; m < 4; ++m)
#pragma unroll
    for (int n = 0; n < 4; ++n) {
      const int col = n0 + wn * 64 + n * 16 + rA;
      const float bv = bias[col];
#pragma unroll
      for (int r = 0; r < 4; ++r) {
        const int row = m0 + wm * 64 + m * 16 + kg * 4 + r;
        float v = acc[m][n][r] + bv;
        if constexpr (RELU_SPLIT) {
          v = fmaxf(v, 0.f);
          u16 hb = f2bf(v);
          u16 lb = f2bf(v - bf2f(hb));
          Chi[(size_t)row * ldC + col] = hb;
          Clo[(size_t)row * ldC + col] = lb;
        } else {
          Cf[(size_t)row * ldC + col] = v;
        }
      }
    }
}

// ---------- no-workspace fp32 fallback (correct, slow) ----------
__global__ __launch_bounds__(256)
void moe_fallback(const float* __restrict__ x, const float* __restrict__ W1,
                  const float* __restrict__ b1, const float* __restrict__ W2,
                  const float* __restrict__ b2, float* __restrict__ out) {
  const int e = blockIdx.y;
  const int r0 = blockIdx.x * 16;
  const int t = threadIdx.x;
  const int r = t >> 4;       // 0..15
  const int cb = t & 15;
  __shared__ float hch[16][516];

  float oacc[64];
#pragma unroll
  for (int j = 0; j < 64; ++j) oacc[j] = 0.f;

  for (int hc0 = 0; hc0 < H_; hc0 += 512) {
    float s[32];
#pragma unroll
    for (int j = 0; j < 32; ++j) s[j] = b1[e * H_ + hc0 + cb + 16 * j];
    for (int d = 0; d < D_; ++d) {
      const float xv = x[(size_t)(r0 + r) * D_ + d];
      const float* w1p = W1 + ((size_t)e * D_ + d) * H_ + hc0 + cb;
#pragma unroll
      for (int j = 0; j < 32; ++j) s[j] = fmaf(xv, w1p[16 * j], s[j]);
    }
    __syncthreads();
#pragma unroll
    for (int j = 0; j < 32; ++j) hch[r][cb + 16 * j] = fmaxf(s[j], 0.f);
    __syncthreads();
    for (int hh = 0; hh < 512; ++hh) {
      const float hv = hch[r][hh];
      const float* w2p = W2 + ((size_t)e * H_ + hc0 + hh) * D_ + cb;
#pragma unroll
      for (int j = 0; j < 64; ++j) oacc[j] = fmaf(hv, w2p[16 * j], oacc[j]);
    }
  }
#pragma unroll
  for (int j = 0; j < 64; ++j) {
    int c = cb + 16 * j;
    out[(size_t)(r0 + r) * (E_ * D_) + (size_t)e * D_ + c] = oacc[j] + b2[e * D_ + c];
  }
}

extern "C" void kernel_launch(void* const* d_in, const int* in_sizes, int n_in,
                              void* d_out, int out_size, void* d_ws, size_t ws_size,
                              hipStream_t stream) {
  (void)in_sizes; (void)n_in; (void)out_size;
  const float* x  = (const float*)d_in[0];
  const float* W1 = (const float*)d_in[1];
  const float* b1 = (const float*)d_in[2];
  const float* W2 = (const float*)d_in[3];
  const float* b2 = (const float*)d_in[4];
  float* out = (float*)d_out;

  const size_t nxd = (size_t)B_ * D_;
  const size_t nw  = (size_t)E_ * D_ * H_;
  const size_t nh  = (size_t)B_ * H_;
  const size_t need = (2 * nxd + 4 * nw + 2 * nh) * sizeof(u16);  // ~185 MB

  if (ws_size < need) {
    moe_fallback<<<dim3(B_ / 16, E_), 256, 0, stream>>>(x, W1, b1, W2, b2, out);
    return;
  }

  u16* p = (u16*)d_ws;
  u16* x_hi   = p; p += nxd;
  u16* x_lo   = p; p += nxd;
  u16* W1T_hi = p; p += nw;   // [E][H][D]
  u16* W1T_lo = p; p += nw;
  u16* W2T_hi = p; p += nw;   // [E][D][H]
  u16* W2T_lo = p; p += nw;
  u16* h_hi   = p; p += nh;   // [B][H], reused per expert
  u16* h_lo   = p; p += nh;

  split_f32<<<dim3((B_ * D_ / 4) / 256), 256, 0, stream>>>(x, x_hi, x_lo, B_ * D_ / 4);
  split_transpose<<<dim3(H_ / 32, D_ / 32, E_), dim3(32, 8), 0, stream>>>(W1, W1T_hi, W1T_lo, D_, H_);
  split_transpose<<<dim3(D_ / 32, H_ / 32, E_), dim3(32, 8), 0, stream>>>(W2, W2T_hi, W2T_lo, H_, D_);

  for (int e = 0; e < E_; ++e) {
    // h = relu(x @ W1_e + b1_e): M=B, N=H, K=D
    gemm_split3<true><<<dim3(H_ / BN, B_ / BM), 256, 0, stream>>>(
        x_hi, x_lo, W1T_hi + (size_t)e * H_ * D_, W1T_lo + (size_t)e * H_ * D_,
        b1 + (size_t)e * H_, h_hi, h_lo, nullptr, D_, H_);
    // out[:, e, :] = h @ W2_e + b2_e: M=B, N=D, K=H
    gemm_split3<false><<<dim3(D_ / BN, B_ / BM), 256, 0, stream>>>(
        h_hi, h_lo, W2T_hi + (size_t)e * D_ * H_, W2T_lo + (size_t)e * D_ * H_,
        b2 + (size_t)e * D_, nullptr, nullptr, out + (size_t)e * D_, H_, E_ * D_);
  }
}

// Round 3
// 1101.234 us; speedup vs baseline: 1.2880x; 1.2880x over previous
//
#include <hip/hip_runtime.h>
#include <cstdint>

#define B_ 4096
#define D_ 1024
#define H_ 2048
#define E_ 8

#define BM 128
#define BN 256
#define BKt 32

typedef __attribute__((ext_vector_type(8))) short short8;
typedef __attribute__((ext_vector_type(4))) float f32x4;
typedef unsigned short u16;
typedef unsigned int u32;

#define MFMA __builtin_amdgcn_mfma_f32_16x16x32_bf16

// ---------- bf16 helpers (RNE) ----------
__device__ __forceinline__ u16 f2bf(float f) {
  u32 u = __builtin_bit_cast(u32, f);
  u32 r = (u + 0x7fffu + ((u >> 16) & 1u)) >> 16;
  return (u16)r;
}
__device__ __forceinline__ float bf2f(u16 h) {
  return __builtin_bit_cast(float, (u32)h << 16);
}

// ---------- async global->LDS, 16B per lane (wave-uniform LDS base) ----------
__device__ __forceinline__ void gld_lds16(const void* g, void* l) {
  __builtin_amdgcn_global_load_lds(
      (const __attribute__((address_space(1))) u32*)(uintptr_t)g,
      (__attribute__((address_space(3))) u32*)(u32)(uintptr_t)l,
      16, 0, 0);
}

// ---------- split fp32 -> bf16 hi/lo ----------
__global__ __launch_bounds__(256)
void split_f32(const float* __restrict__ in, u16* __restrict__ hi,
               u16* __restrict__ lo, int n4) {
  int i = blockIdx.x * 256 + threadIdx.x;
  if (i >= n4) return;
  float4 v = ((const float4*)in)[i];
  float a[4] = {v.x, v.y, v.z, v.w};
  u16 hb[4], lb[4];
#pragma unroll
  for (int j = 0; j < 4; ++j) {
    hb[j] = f2bf(a[j]);
    lb[j] = f2bf(a[j] - bf2f(hb[j]));
  }
  ((ushort4*)hi)[i] = make_ushort4(hb[0], hb[1], hb[2], hb[3]);
  ((ushort4*)lo)[i] = make_ushort4(lb[0], lb[1], lb[2], lb[3]);
}

// ---------- split + transpose: in [E][R][C] fp32 -> out [E][C][R] bf16 hi/lo ----------
__global__ __launch_bounds__(256)
void split_transpose(const float* __restrict__ in, u16* __restrict__ thi,
                     u16* __restrict__ tlo, int R, int C) {
  __shared__ float t[32][33];
  const int e = blockIdx.z;
  const size_t base = (size_t)e * R * C;
  const int c0 = blockIdx.x * 32, r0 = blockIdx.y * 32;
  const int tx = threadIdx.x, ty = threadIdx.y;
#pragma unroll
  for (int i = 0; i < 32; i += 8)
    t[ty + i][tx] = in[base + (size_t)(r0 + ty + i) * C + (c0 + tx)];
  __syncthreads();
#pragma unroll
  for (int i = 0; i < 32; i += 8) {
    float v = t[tx][ty + i];
    u16 hb = f2bf(v);
    u16 lb = f2bf(v - bf2f(hb));
    size_t oidx = base + (size_t)(c0 + ty + i) * R + (r0 + tx);
    thi[oidx] = hb;
    tlo[oidx] = lb;
  }
}

// ---------- split-3 MFMA GEMM, 3-deep pipeline, counted vmcnt, setprio ----------
// C[M x N] = A[M x K] * Bt[N x K]^T, acc = Ah*Bh + Ah*Bl + Al*Bh (fp32).
// 512 threads (8 waves: wm = w>>2 in {0,1} over M-halves, wn = w&3 over N-quads).
// LDS: 3 buffers x {Ah[128][32] | Al[128][32] | Bh[256][32] | Bl[256][32]} = 144 KB.
// Per K-tile: 2 phases x {ds_read frags; 3x global_load_lds (tile kt+2);
//   s_barrier; lgkmcnt(0); sched_barrier; setprio(1); 24 MFMA; setprio(0);
//   [vmcnt(6) at K-tile end]; s_barrier}.
// EPI 0: relu(acc+bias) re-split to bf16 hi/lo. EPI 1: fp32 store acc+bias.
template <int EPI>
__global__ __launch_bounds__(512, 2)
void gemm8p(const u16* __restrict__ Ah, const u16* __restrict__ Al,
            const u16* __restrict__ Bth, const u16* __restrict__ Btl,
            const float* __restrict__ bias,
            u16* __restrict__ Chi, u16* __restrict__ Clo, float* __restrict__ Cf,
            int K, int Nt, int tiles_per_e,
            size_t sAe, size_t sBe, size_t sBias, size_t sC, int ldC) {
  __shared__ u16 L[3][768 * 32];  // 3 x 48 KB

  // XCD-aware bijective swizzle (all grids are %8==0)
  const int nwg = gridDim.x;
  const int q = nwg >> 3;
  const int orig = blockIdx.x;
  const int id = (orig & 7) * q + (orig >> 3);
  const int e = id / tiles_per_e;
  const int t = id % tiles_per_e;
  const int bm = t / Nt, bn = t % Nt;
  const int m0 = bm * BM, n0 = bn * BN;

  Ah  += (size_t)e * sAe;  Al  += (size_t)e * sAe;
  Bth += (size_t)e * sBe;  Btl += (size_t)e * sBe;
  bias += (size_t)e * sBias;
  u16* ChiE = nullptr; u16* CloE = nullptr; float* CfE = nullptr;
  if constexpr (EPI == 0) { ChiE = Chi + (size_t)e * sC; CloE = Clo + (size_t)e * sC; }
  else { CfE = Cf + (size_t)e * sC; }

  const int tid = threadIdx.x;
  const int w = tid >> 6, lane = tid & 63;
  const int wm = w >> 2, wn = w & 3;
  const int rA = lane & 15, kg = lane >> 4;
  const int srow = tid >> 2;        // staging row within a 128-row half
  const int scol = (tid & 3) * 8;   // staging col element
  const int wrow = w << 4;          // wave-uniform LDS row base within a half

  f32x4 acc[4][4];
#pragma unroll
  for (int m = 0; m < 4; ++m)
#pragma unroll
    for (int n = 0; n < 4; ++n) acc[m][n] = (f32x4){0.f, 0.f, 0.f, 0.f};

  // stage load j of K-tile kt into buffer sb.
  // j: 0=Ah, 1=Al, 2=Bh half0, 3=Bh half1, 4=Bl half0, 5=Bl half1
  auto STAGE = [&](int sb, int kt, int j) {
    const int k0 = kt * BKt;
    const u16* src; int lr;
    switch (j) {
      case 0:  src = Ah  + (size_t)(m0 + srow) * K + (k0 + scol);       lr = 0   + wrow; break;
      case 1:  src = Al  + (size_t)(m0 + srow) * K + (k0 + scol);       lr = 128 + wrow; break;
      case 2:  src = Bth + (size_t)(n0 + srow) * K + (k0 + scol);       lr = 256 + wrow; break;
      case 3:  src = Bth + (size_t)(n0 + 128 + srow) * K + (k0 + scol); lr = 384 + wrow; break;
      case 4:  src = Btl + (size_t)(n0 + srow) * K + (k0 + scol);       lr = 512 + wrow; break;
      default: src = Btl + (size_t)(n0 + 128 + srow) * K + (k0 + scol); lr = 640 + wrow; break;
    }
    gld_lds16(src, &L[sb][(u32)lr * 32]);
  };

  short8 bh[4], bl[4];
  auto LDB = [&](int cb) {
#pragma unroll
    for (int n = 0; n < 4; ++n) {
      const int r = wn * 64 + n * 16 + rA;
      bh[n] = *(const short8*)&L[cb][(u32)(256 + r) * 32 + kg * 8];
      bl[n] = *(const short8*)&L[cb][(u32)(512 + r) * 32 + kg * 8];
    }
  };
  auto LDA2 = [&](int cb, int mq, short8* ah, short8* al) {
#pragma unroll
    for (int m = 0; m < 2; ++m) {
      const int r = wm * 64 + (mq + m) * 16 + rA;
      ah[m] = *(const short8*)&L[cb][(u32)r * 32 + kg * 8];
      al[m] = *(const short8*)&L[cb][(u32)(128 + r) * 32 + kg * 8];
    }
  };

  // prologue: stage tiles 0 and 1; wait for tile 0 (leave tile 1 in flight)
#pragma unroll
  for (int j = 0; j < 6; ++j) STAGE(0, 0, j);
#pragma unroll
  for (int j = 0; j < 6; ++j) STAGE(1, 1, j);
  asm volatile("s_waitcnt vmcnt(6)" ::: "memory");
  __builtin_amdgcn_s_barrier();

  const int NT = K >> 5;
  int cb = 0;
  for (int i = 0; i < NT; ++i) {
    const bool stg = (i < NT - 2);
    const int sb = (cb >= 1) ? cb - 1 : 2;  // (cb+2)%3
    const int kt = i + 2;
    short8 ah[2], al[2];

    // ---- phase A: m-subtiles 0,1 ----
    LDA2(cb, 0, ah, al);
    LDB(cb);
    if (stg) { STAGE(sb, kt, 0); STAGE(sb, kt, 1); STAGE(sb, kt, 2); }
    __builtin_amdgcn_s_barrier();
    asm volatile("s_waitcnt lgkmcnt(0)" ::: "memory");
    __builtin_amdgcn_sched_barrier(0);
    __builtin_amdgcn_s_setprio(1);
#pragma unroll
    for (int m = 0; m < 2; ++m)
#pragma unroll
      for (int n = 0; n < 4; ++n) {
        f32x4 a = acc[m][n];
        a = MFMA(ah[m], bh[n], a, 0, 0, 0);
        a = MFMA(ah[m], bl[n], a, 0, 0, 0);
        a = MFMA(al[m], bh[n], a, 0, 0, 0);
        acc[m][n] = a;
      }
    __builtin_amdgcn_s_setprio(0);
    __builtin_amdgcn_s_barrier();

    // ---- phase B: m-subtiles 2,3 ----
    LDA2(cb, 2, ah, al);
    if (stg) { STAGE(sb, kt, 3); STAGE(sb, kt, 4); STAGE(sb, kt, 5); }
    __builtin_amdgcn_s_barrier();
    asm volatile("s_waitcnt lgkmcnt(0)" ::: "memory");
    __builtin_amdgcn_sched_barrier(0);
    __builtin_amdgcn_s_setprio(1);
#pragma unroll
    for (int m = 0; m < 2; ++m)
#pragma unroll
      for (int n = 0; n < 4; ++n) {
        f32x4 a = acc[2 + m][n];
        a = MFMA(ah[m], bh[n], a, 0, 0, 0);
        a = MFMA(ah[m], bl[n], a, 0, 0, 0);
        a = MFMA(al[m], bh[n], a, 0, 0, 0);
        acc[2 + m][n] = a;
      }
    __builtin_amdgcn_s_setprio(0);
    if (stg) {
      asm volatile("s_waitcnt vmcnt(6)" ::: "memory");  // tile i+1 ready; tile i+2 in flight
    } else if (i == NT - 2) {
      asm volatile("s_waitcnt vmcnt(0)" ::: "memory");  // epilogue drain
    }
    __builtin_amdgcn_s_barrier();
    cb = (cb == 2) ? 0 : cb + 1;
  }

  // ---- epilogue: C/D layout col=lane&15, row=(lane>>4)*4+reg [verified r2] ----
#pragma unroll
  for (int m = 0; m < 4; ++m)
#pragma unroll
    for (int n = 0; n < 4; ++n) {
      const int col = n0 + wn * 64 + n * 16 + rA;
      const float bv = bias[col];
#pragma unroll
      for (int r = 0; r < 4; ++r) {
        const int row = m0 + wm * 64 + m * 16 + kg * 4 + r;
        float v = acc[m][n][r] + bv;
        if constexpr (EPI == 0) {
          v = fmaxf(v, 0.f);
          u16 hb = f2bf(v);
          u16 lb = f2bf(v - bf2f(hb));
          ChiE[(size_t)row * ldC + col] = hb;
          CloE[(size_t)row * ldC + col] = lb;
        } else {
          CfE[(size_t)row * ldC + col] = v;
        }
      }
    }
}

// ---------- no-workspace fp32 fallback (correct, slow) ----------
__global__ __launch_bounds__(256)
void moe_fallback(const float* __restrict__ x, const float* __restrict__ W1,
                  const float* __restrict__ b1, const float* __restrict__ W2,
                  const float* __restrict__ b2, float* __restrict__ out) {
  const int e = blockIdx.y;
  const int r0 = blockIdx.x * 16;
  const int t = threadIdx.x;
  const int r = t >> 4;
  const int cb = t & 15;
  __shared__ float hch[16][516];

  float oacc[64];
#pragma unroll
  for (int j = 0; j < 64; ++j) oacc[j] = 0.f;

  for (int hc0 = 0; hc0 < H_; hc0 += 512) {
    float s[32];
#pragma unroll
    for (int j = 0; j < 32; ++j) s[j] = b1[e * H_ + hc0 + cb + 16 * j];
    for (int d = 0; d < D_; ++d) {
      const float xv = x[(size_t)(r0 + r) * D_ + d];
      const float* w1p = W1 + ((size_t)e * D_ + d) * H_ + hc0 + cb;
#pragma unroll
      for (int j = 0; j < 32; ++j) s[j] = fmaf(xv, w1p[16 * j], s[j]);
    }
    __syncthreads();
#pragma unroll
    for (int j = 0; j < 32; ++j) hch[r][cb + 16 * j] = fmaxf(s[j], 0.f);
    __syncthreads();
    for (int hh = 0; hh < 512; ++hh) {
      const float hv = hch[r][hh];
      const float* w2p = W2 + ((size_t)e * H_ + hc0 + hh) * D_ + cb;
#pragma unroll
      for (int j = 0; j < 64; ++j) oacc[j] = fmaf(hv, w2p[16 * j], oacc[j]);
    }
  }
#pragma unroll
  for (int j = 0; j < 64; ++j) {
    int c = cb + 16 * j;
    out[(size_t)(r0 + r) * (E_ * D_) + (size_t)e * D_ + c] = oacc[j] + b2[e * D_ + c];
  }
}

extern "C" void kernel_launch(void* const* d_in, const int* in_sizes, int n_in,
                              void* d_out, int out_size, void* d_ws, size_t ws_size,
                              hipStream_t stream) {
  (void)in_sizes; (void)n_in; (void)out_size;
  const float* x  = (const float*)d_in[0];
  const float* W1 = (const float*)d_in[1];
  const float* b1 = (const float*)d_in[2];
  const float* W2 = (const float*)d_in[3];
  const float* b2 = (const float*)d_in[4];
  float* out = (float*)d_out;

  const size_t nxd = (size_t)B_ * D_;
  const size_t nw  = (size_t)E_ * D_ * H_;
  const size_t nh1 = (size_t)B_ * H_;
  const size_t needP = (2 * nxd + 4 * nw + 4 * nh1) * sizeof(u16);  // 208 MB (paired h)
  const size_t needS = (2 * nxd + 4 * nw + 2 * nh1) * sizeof(u16);  // 176 MB (single h)

  if (ws_size < needS) {
    moe_fallback<<<dim3(B_ / 16, E_), 256, 0, stream>>>(x, W1, b1, W2, b2, out);
    return;
  }

  const bool paired = (ws_size >= needP);

  u16* p = (u16*)d_ws;
  u16* x_hi   = p; p += nxd;
  u16* x_lo   = p; p += nxd;
  u16* W1T_hi = p; p += nw;   // [E][H][D]
  u16* W1T_lo = p; p += nw;
  u16* W2T_hi = p; p += nw;   // [E][D][H]
  u16* W2T_lo = p; p += nw;
  u16* h_hi   = p; p += paired ? 2 * nh1 : nh1;  // [1|2][B][H]
  u16* h_lo   = p;

  split_f32<<<dim3((B_ * D_ / 4) / 256), 256, 0, stream>>>(x, x_hi, x_lo, B_ * D_ / 4);
  split_transpose<<<dim3(H_ / 32, D_ / 32, E_), dim3(32, 8), 0, stream>>>(W1, W1T_hi, W1T_lo, D_, H_);
  split_transpose<<<dim3(D_ / 32, H_ / 32, E_), dim3(32, 8), 0, stream>>>(W2, W2T_hi, W2T_lo, H_, D_);

  const int t1 = (B_ / BM) * (H_ / BN);  // 256 tiles per expert, GEMM1
  const int t2 = (B_ / BM) * (D_ / BN);  // 128 tiles per expert, GEMM2

  if (paired) {
    for (int ep = 0; ep < E_ / 2; ++ep) {
      for (int hs = 0; hs < 2; ++hs) {
        const int e = 2 * ep + hs;
        gemm8p<0><<<t1, 512, 0, stream>>>(
            x_hi, x_lo, W1T_hi + (size_t)e * H_ * D_, W1T_lo + (size_t)e * H_ * D_,
            b1 + (size_t)e * H_,
            h_hi + (size_t)hs * nh1, h_lo + (size_t)hs * nh1, nullptr,
            D_, H_ / BN, t1, 0, 0, 0, 0, H_);
      }
      gemm8p<1><<<2 * t2, 512, 0, stream>>>(
          h_hi, h_lo, W2T_hi + (size_t)(2 * ep) * D_ * H_, W2T_lo + (size_t)(2 * ep) * D_ * H_,
          b2 + (size_t)(2 * ep) * D_,
          nullptr, nullptr, out + (size_t)(2 * ep) * D_,
          H_, D_ / BN, t2, nh1, (size_t)D_ * H_, D_, D_, E_ * D_);
    }
  } else {
    for (int e = 0; e < E_; ++e) {
      gemm8p<0><<<t1, 512, 0, stream>>>(
          x_hi, x_lo, W1T_hi + (size_t)e * H_ * D_, W1T_lo + (size_t)e * H_ * D_,
          b1 + (size_t)e * H_, h_hi, h_lo, nullptr,
          D_, H_ / BN, t1, 0, 0, 0, 0, H_);
      gemm8p<1><<<t2, 512, 0, stream>>>(
          h_hi, h_lo, W2T_hi + (size_t)e * D_ * H_, W2T_lo + (size_t)e * D_ * H_,
          b2 + (size_t)e * D_, nullptr, nullptr, out + (size_t)e * D_,
          H_, D_ / BN, t2, 0, (size_t)D_ * H_, 0, 0, E_ * D_);
    }
  }
}

// Round 4
// 1044.508 us; speedup vs baseline: 1.3580x; 1.0543x over previous
//
#include <hip/hip_runtime.h>
#include <cstdint>

#define B_ 4096
#define D_ 1024
#define H_ 2048
#define E_ 8

#define BM 128
#define BN 256
#define BKt 32

typedef __attribute__((ext_vector_type(8))) short short8;
typedef __attribute__((ext_vector_type(4))) float f32x4;
typedef unsigned short u16;
typedef unsigned int u32;

#define MFMA __builtin_amdgcn_mfma_f32_16x16x32_bf16

// ---------- bf16 helpers (RNE) ----------
__device__ __forceinline__ u16 f2bf(float f) {
  u32 u = __builtin_bit_cast(u32, f);
  u32 r = (u + 0x7fffu + ((u >> 16) & 1u)) >> 16;
  return (u16)r;
}
__device__ __forceinline__ float bf2f(u16 h) {
  return __builtin_bit_cast(float, (u32)h << 16);
}

// ---------- async global->LDS, 16B per lane (wave-uniform LDS base) ----------
__device__ __forceinline__ void gld_lds16(const void* g, void* l) {
  __builtin_amdgcn_global_load_lds(
      (const __attribute__((address_space(1))) u32*)(uintptr_t)g,
      (__attribute__((address_space(3))) u32*)(u32)(uintptr_t)l,
      16, 0, 0);
}

// ---------- split fp32 -> bf16 hi/lo ----------
__global__ __launch_bounds__(256)
void split_f32(const float* __restrict__ in, u16* __restrict__ hi,
               u16* __restrict__ lo, int n4) {
  int i = blockIdx.x * 256 + threadIdx.x;
  if (i >= n4) return;
  float4 v = ((const float4*)in)[i];
  float a[4] = {v.x, v.y, v.z, v.w};
  u16 hb[4], lb[4];
#pragma unroll
  for (int j = 0; j < 4; ++j) {
    hb[j] = f2bf(a[j]);
    lb[j] = f2bf(a[j] - bf2f(hb[j]));
  }
  ((ushort4*)hi)[i] = make_ushort4(hb[0], hb[1], hb[2], hb[3]);
  ((ushort4*)lo)[i] = make_ushort4(lb[0], lb[1], lb[2], lb[3]);
}

// ---------- split + transpose: in [E][R][C] fp32 -> out [E][C][R] bf16 hi/lo ----------
__global__ __launch_bounds__(256)
void split_transpose(const float* __restrict__ in, u16* __restrict__ thi,
                     u16* __restrict__ tlo, int R, int C) {
  __shared__ float t[32][33];
  const int e = blockIdx.z;
  const size_t base = (size_t)e * R * C;
  const int c0 = blockIdx.x * 32, r0 = blockIdx.y * 32;
  const int tx = threadIdx.x, ty = threadIdx.y;
#pragma unroll
  for (int i = 0; i < 32; i += 8)
    t[ty + i][tx] = in[base + (size_t)(r0 + ty + i) * C + (c0 + tx)];
  __syncthreads();
#pragma unroll
  for (int i = 0; i < 32; i += 8) {
    float v = t[tx][ty + i];
    u16 hb = f2bf(v);
    u16 lb = f2bf(v - bf2f(hb));
    size_t oidx = base + (size_t)(c0 + ty + i) * R + (r0 + tx);
    thi[oidx] = hb;
    tlo[oidx] = lb;
  }
}

// ---------- split-3 MFMA GEMM, 3-deep pipeline, counted vmcnt, setprio ----------
// C[M x N] = A[M x K] * Bt[N x K]^T, acc = Ah*Bh + Ah*Bl + Al*Bh (fp32).
// LDS rows are 64 B (BKt=32 bf16). Bank-conflict swizzle: 16B-chunk c of row r
// stored at chunk c ^ ((r>>1)&3). Applied on the STAGE side by pre-swizzling
// the per-lane GLOBAL source column (LDS dest stays linear — global_load_lds
// rule), and on the read side in the frag chunk index. Region bases are
// multiples of 128 rows so (r>>1)&3 is region-invariant.
template <int EPI>
__global__ __launch_bounds__(512, 2)
void gemm8p(const u16* __restrict__ Ah, const u16* __restrict__ Al,
            const u16* __restrict__ Bth, const u16* __restrict__ Btl,
            const float* __restrict__ bias,
            u16* __restrict__ Chi, u16* __restrict__ Clo, float* __restrict__ Cf,
            int K, int Nt, int tiles_per_e,
            size_t sAe, size_t sBe, size_t sBias, size_t sC, int ldC) {
  __shared__ u16 L[3][768 * 32];  // 3 x 48 KB

  // XCD-aware bijective swizzle (all grids are %8==0)
  const int nwg = gridDim.x;
  const int q = nwg >> 3;
  const int orig = blockIdx.x;
  const int id = (orig & 7) * q + (orig >> 3);
  const int e = id / tiles_per_e;
  const int t = id % tiles_per_e;
  const int bm = t / Nt, bn = t % Nt;
  const int m0 = bm * BM, n0 = bn * BN;

  Ah  += (size_t)e * sAe;  Al  += (size_t)e * sAe;
  Bth += (size_t)e * sBe;  Btl += (size_t)e * sBe;
  bias += (size_t)e * sBias;
  u16* ChiE = nullptr; u16* CloE = nullptr; float* CfE = nullptr;
  if constexpr (EPI == 0) { ChiE = Chi + (size_t)e * sC; CloE = Clo + (size_t)e * sC; }
  else { CfE = Cf + (size_t)e * sC; }

  const int tid = threadIdx.x;
  const int w = tid >> 6, lane = tid & 63;
  const int wm = w >> 2, wn = w & 3;
  const int rA = lane & 15, kg = lane >> 4;
  const int srow = tid >> 2;                             // staging row (0..127)
  const int scol = (((tid & 3) ^ ((srow >> 1) & 3)) * 8); // pre-swizzled src col
  const int wrow = w << 4;                               // wave LDS row base

  f32x4 acc[4][4];
#pragma unroll
  for (int m = 0; m < 4; ++m)
#pragma unroll
    for (int n = 0; n < 4; ++n) acc[m][n] = (f32x4){0.f, 0.f, 0.f, 0.f};

  // stage load j of K-tile kt into buffer sb.
  // j: 0=Ah, 1=Al, 2=Bh half0, 3=Bh half1, 4=Bl half0, 5=Bl half1
  auto STAGE = [&](int sb, int kt, int j) {
    const int k0 = kt * BKt;
    const u16* src; int lr;
    switch (j) {
      case 0:  src = Ah  + (size_t)(m0 + srow) * K + (k0 + scol);       lr = 0   + wrow; break;
      case 1:  src = Al  + (size_t)(m0 + srow) * K + (k0 + scol);       lr = 128 + wrow; break;
      case 2:  src = Bth + (size_t)(n0 + srow) * K + (k0 + scol);       lr = 256 + wrow; break;
      case 3:  src = Bth + (size_t)(n0 + 128 + srow) * K + (k0 + scol); lr = 384 + wrow; break;
      case 4:  src = Btl + (size_t)(n0 + srow) * K + (k0 + scol);       lr = 512 + wrow; break;
      default: src = Btl + (size_t)(n0 + 128 + srow) * K + (k0 + scol); lr = 640 + wrow; break;
    }
    gld_lds16(src, &L[sb][(u32)lr * 32]);
  };

  short8 bh[4], bl[4];
  auto LDB = [&](int cb) {
#pragma unroll
    for (int n = 0; n < 4; ++n) {
      const int r = wn * 64 + n * 16 + rA;
      const int cc = (kg ^ ((r >> 1) & 3)) * 8;  // swizzled chunk
      bh[n] = *(const short8*)&L[cb][(u32)(256 + r) * 32 + cc];
      bl[n] = *(const short8*)&L[cb][(u32)(512 + r) * 32 + cc];
    }
  };
  auto LDA2 = [&](int cb, int mq, short8* ah, short8* al) {
#pragma unroll
    for (int m = 0; m < 2; ++m) {
      const int r = wm * 64 + (mq + m) * 16 + rA;
      const int cc = (kg ^ ((r >> 1) & 3)) * 8;  // swizzled chunk
      ah[m] = *(const short8*)&L[cb][(u32)r * 32 + cc];
      al[m] = *(const short8*)&L[cb][(u32)(128 + r) * 32 + cc];
    }
  };

  // prologue: stage tiles 0 and 1; wait for tile 0 (leave tile 1 in flight)
#pragma unroll
  for (int j = 0; j < 6; ++j) STAGE(0, 0, j);
#pragma unroll
  for (int j = 0; j < 6; ++j) STAGE(1, 1, j);
  asm volatile("s_waitcnt vmcnt(6)" ::: "memory");
  __builtin_amdgcn_s_barrier();

  const int NT = K >> 5;
  int cb = 0;
  for (int i = 0; i < NT; ++i) {
    const bool stg = (i < NT - 2);
    const int sb = (cb >= 1) ? cb - 1 : 2;  // (cb+2)%3
    const int kt = i + 2;
    short8 ah[2], al[2];

    // ---- phase A: m-subtiles 0,1 ----
    LDA2(cb, 0, ah, al);
    LDB(cb);
    if (stg) { STAGE(sb, kt, 0); STAGE(sb, kt, 1); STAGE(sb, kt, 2); }
    __builtin_amdgcn_s_barrier();
    asm volatile("s_waitcnt lgkmcnt(0)" ::: "memory");
    __builtin_amdgcn_sched_barrier(0);
    __builtin_amdgcn_s_setprio(1);
#pragma unroll
    for (int m = 0; m < 2; ++m)
#pragma unroll
      for (int n = 0; n < 4; ++n) {
        f32x4 a = acc[m][n];
        a = MFMA(ah[m], bh[n], a, 0, 0, 0);
        a = MFMA(ah[m], bl[n], a, 0, 0, 0);
        a = MFMA(al[m], bh[n], a, 0, 0, 0);
        acc[m][n] = a;
      }
    __builtin_amdgcn_s_setprio(0);
    __builtin_amdgcn_s_barrier();

    // ---- phase B: m-subtiles 2,3 ----
    LDA2(cb, 2, ah, al);
    if (stg) { STAGE(sb, kt, 3); STAGE(sb, kt, 4); STAGE(sb, kt, 5); }
    __builtin_amdgcn_s_barrier();
    asm volatile("s_waitcnt lgkmcnt(0)" ::: "memory");
    __builtin_amdgcn_sched_barrier(0);
    __builtin_amdgcn_s_setprio(1);
#pragma unroll
    for (int m = 0; m < 2; ++m)
#pragma unroll
      for (int n = 0; n < 4; ++n) {
        f32x4 a = acc[2 + m][n];
        a = MFMA(ah[m], bh[n], a, 0, 0, 0);
        a = MFMA(ah[m], bl[n], a, 0, 0, 0);
        a = MFMA(al[m], bh[n], a, 0, 0, 0);
        acc[2 + m][n] = a;
      }
    __builtin_amdgcn_s_setprio(0);
    if (stg) {
      asm volatile("s_waitcnt vmcnt(6)" ::: "memory");  // tile i+1 ready; i+2 in flight
    } else if (i == NT - 2) {
      asm volatile("s_waitcnt vmcnt(0)" ::: "memory");  // epilogue drain
    }
    __builtin_amdgcn_s_barrier();
    cb = (cb == 2) ? 0 : cb + 1;
  }

  // ---- epilogue: C/D layout col=lane&15, row=(lane>>4)*4+reg [verified r2] ----
#pragma unroll
  for (int m = 0; m < 4; ++m)
#pragma unroll
    for (int n = 0; n < 4; ++n) {
      const int col = n0 + wn * 64 + n * 16 + rA;
      const float bv = bias[col];
#pragma unroll
      for (int r = 0; r < 4; ++r) {
        const int row = m0 + wm * 64 + m * 16 + kg * 4 + r;
        float v = acc[m][n][r] + bv;
        if constexpr (EPI == 0) {
          v = fmaxf(v, 0.f);
          u16 hb = f2bf(v);
          u16 lb = f2bf(v - bf2f(hb));
          ChiE[(size_t)row * ldC + col] = hb;
          CloE[(size_t)row * ldC + col] = lb;
        } else {
          CfE[(size_t)row * ldC + col] = v;
        }
      }
    }
}

// ---------- no-workspace fp32 fallback (correct, slow) ----------
__global__ __launch_bounds__(256)
void moe_fallback(const float* __restrict__ x, const float* __restrict__ W1,
                  const float* __restrict__ b1, const float* __restrict__ W2,
                  const float* __restrict__ b2, float* __restrict__ out) {
  const int e = blockIdx.y;
  const int r0 = blockIdx.x * 16;
  const int t = threadIdx.x;
  const int r = t >> 4;
  const int cb = t & 15;
  __shared__ float hch[16][516];

  float oacc[64];
#pragma unroll
  for (int j = 0; j < 64; ++j) oacc[j] = 0.f;

  for (int hc0 = 0; hc0 < H_; hc0 += 512) {
    float s[32];
#pragma unroll
    for (int j = 0; j < 32; ++j) s[j] = b1[e * H_ + hc0 + cb + 16 * j];
    for (int d = 0; d < D_; ++d) {
      const float xv = x[(size_t)(r0 + r) * D_ + d];
      const float* w1p = W1 + ((size_t)e * D_ + d) * H_ + hc0 + cb;
#pragma unroll
      for (int j = 0; j < 32; ++j) s[j] = fmaf(xv, w1p[16 * j], s[j]);
    }
    __syncthreads();
#pragma unroll
    for (int j = 0; j < 32; ++j) hch[r][cb + 16 * j] = fmaxf(s[j], 0.f);
    __syncthreads();
    for (int hh = 0; hh < 512; ++hh) {
      const float hv = hch[r][hh];
      const float* w2p = W2 + ((size_t)e * H_ + hc0 + hh) * D_ + cb;
#pragma unroll
      for (int j = 0; j < 64; ++j) oacc[j] = fmaf(hv, w2p[16 * j], oacc[j]);
    }
  }
#pragma unroll
  for (int j = 0; j < 64; ++j) {
    int c = cb + 16 * j;
    out[(size_t)(r0 + r) * (E_ * D_) + (size_t)e * D_ + c] = oacc[j] + b2[e * D_ + c];
  }
}

extern "C" void kernel_launch(void* const* d_in, const int* in_sizes, int n_in,
                              void* d_out, int out_size, void* d_ws, size_t ws_size,
                              hipStream_t stream) {
  (void)in_sizes; (void)n_in; (void)out_size;
  const float* x  = (const float*)d_in[0];
  const float* W1 = (const float*)d_in[1];
  const float* b1 = (const float*)d_in[2];
  const float* W2 = (const float*)d_in[3];
  const float* b2 = (const float*)d_in[4];
  float* out = (float*)d_out;

  const size_t nxd = (size_t)B_ * D_;
  const size_t nw  = (size_t)E_ * D_ * H_;
  const size_t nh1 = (size_t)B_ * H_;
  const size_t needP = (2 * nxd + 4 * nw + 4 * nh1) * sizeof(u16);  // 208 MB (paired h)
  const size_t needS = (2 * nxd + 4 * nw + 2 * nh1) * sizeof(u16);  // 176 MB (single h)

  if (ws_size < needS) {
    moe_fallback<<<dim3(B_ / 16, E_), 256, 0, stream>>>(x, W1, b1, W2, b2, out);
    return;
  }

  const bool paired = (ws_size >= needP);

  u16* p = (u16*)d_ws;
  u16* x_hi   = p; p += nxd;
  u16* x_lo   = p; p += nxd;
  u16* W1T_hi = p; p += nw;   // [E][H][D]
  u16* W1T_lo = p; p += nw;
  u16* W2T_hi = p; p += nw;   // [E][D][H]
  u16* W2T_lo = p; p += nw;
  u16* h_hi   = p; p += paired ? 2 * nh1 : nh1;  // [1|2][B][H]
  u16* h_lo   = p;

  split_f32<<<dim3((B_ * D_ / 4) / 256), 256, 0, stream>>>(x, x_hi, x_lo, B_ * D_ / 4);
  split_transpose<<<dim3(H_ / 32, D_ / 32, E_), dim3(32, 8), 0, stream>>>(W1, W1T_hi, W1T_lo, D_, H_);
  split_transpose<<<dim3(D_ / 32, H_ / 32, E_), dim3(32, 8), 0, stream>>>(W2, W2T_hi, W2T_lo, H_, D_);

  const int t1 = (B_ / BM) * (H_ / BN);  // 256 tiles per expert, GEMM1
  const int t2 = (B_ / BM) * (D_ / BN);  // 128 tiles per expert, GEMM2

  if (paired) {
    for (int ep = 0; ep < E_ / 2; ++ep) {
      for (int hs = 0; hs < 2; ++hs) {
        const int e = 2 * ep + hs;
        gemm8p<0><<<t1, 512, 0, stream>>>(
            x_hi, x_lo, W1T_hi + (size_t)e * H_ * D_, W1T_lo + (size_t)e * H_ * D_,
            b1 + (size_t)e * H_,
            h_hi + (size_t)hs * nh1, h_lo + (size_t)hs * nh1, nullptr,
            D_, H_ / BN, t1, 0, 0, 0, 0, H_);
      }
      gemm8p<1><<<2 * t2, 512, 0, stream>>>(
          h_hi, h_lo, W2T_hi + (size_t)(2 * ep) * D_ * H_, W2T_lo + (size_t)(2 * ep) * D_ * H_,
          b2 + (size_t)(2 * ep) * D_,
          nullptr, nullptr, out + (size_t)(2 * ep) * D_,
          H_, D_ / BN, t2, nh1, (size_t)D_ * H_, D_, D_, E_ * D_);
    }
  } else {
    for (int e = 0; e < E_; ++e) {
      gemm8p<0><<<t1, 512, 0, stream>>>(
          x_hi, x_lo, W1T_hi + (size_t)e * H_ * D_, W1T_lo + (size_t)e * H_ * D_,
          b1 + (size_t)e * H_, h_hi, h_lo, nullptr,
          D_, H_ / BN, t1, 0, 0, 0, 0, H_);
      gemm8p<1><<<t2, 512, 0, stream>>>(
          h_hi, h_lo, W2T_hi + (size_t)e * D_ * H_, W2T_lo + (size_t)e * D_ * H_,
          b2 + (size_t)e * D_, nullptr, nullptr, out + (size_t)e * D_,
          H_, D_ / BN, t2, 0, (size_t)D_ * H_, 0, 0, E_ * D_);
    }
  }
}